// Round 5
// baseline (1133.566 us; speedup 1.0000x reference)
//
#include <hip/hip_runtime.h>
#include <cstdint>
#include <cstddef>

#define E_ 8
#define T_ 1024
#define D_ 1024
#define I_ 5632
#define TWO_I_ 11264
#define NPAD_MAX 2176                 /* 2048 + 8*16 */

// ws layout (bytes): int tables in [0,64K), then act_f, then xg_f, y overlays xg_f
#define WS_ACTF_B 65536
#define WS_XGF_B  (65536 + 24510464)              /* act_f = 136*180224      */
#define WS_Y_B    WS_XGF_B                        /* y overlays dead xg_f    */
// int-table offsets (units of 4 B)
#define WS_CNT   0
#define WS_BASEP 8
#define WS_ESLOT 16
#define WS_TOKW  2064
#define WS_ETOK  4112

typedef __attribute__((ext_vector_type(8))) __bf16 bf16x8;
typedef __attribute__((ext_vector_type(4))) float  f32x4;

__device__ __forceinline__ unsigned f2bf(float f) {
    unsigned u = __float_as_uint(f);
    u += 0x7fffu + ((u >> 16) & 1u);
    return u >> 16;
}
__device__ __forceinline__ unsigned pack2bf(float f0, float f1) {
    unsigned a0 = __float_as_uint(f0); a0 += 0x7fffu + ((a0 >> 16) & 1u);
    unsigned a1 = __float_as_uint(f1); a1 += 0x7fffu + ((a1 >> 16) & 1u);
    return (a0 >> 16) | (a1 & 0xffff0000u);
}

// ---------------------------------------------------------------- routing ---
__global__ void routing_kernel(const float* __restrict__ gate,
                               int* cnt, int* basep, int* eslot,
                               float* tokw, int* etok)
{
    int t = threadIdx.x;
    if (t < E_) cnt[t] = 0;
    __syncthreads();
    float g[E_];
#pragma unroll
    for (int e = 0; e < E_; ++e) g[e] = gate[t * E_ + e];
    int i0 = 0; float p0 = g[0];
#pragma unroll
    for (int e = 1; e < E_; ++e) if (g[e] > p0) { p0 = g[e]; i0 = e; }
    int i1 = -1; float p1 = -1e30f;
#pragma unroll
    for (int e = 0; e < E_; ++e) if (e != i0 && g[e] > p1) { p1 = g[e]; i1 = e; }
    float w0 = 1.0f / (1.0f + expf(p1 - p0));
    float w1 = 1.0f - w0;
    int s0 = atomicAdd(&cnt[i0], 1);
    int s1 = atomicAdd(&cnt[i1], 1);
    etok[i0 * T_ + s0] = t;
    etok[i1 * T_ + s1] = t;
    eslot[t * 2 + 0] = i0 * T_ + s0;  tokw[t * 2 + 0] = w0;
    eslot[t * 2 + 1] = i1 * T_ + s1;  tokw[t * 2 + 1] = w1;
    __syncthreads();
    if (t == 0) {
        int r = 0;
#pragma unroll
        for (int e = 0; e < E_; ++e) { basep[e] = r; r += (cnt[e] + 15) & ~15; }
    }
}

// ------------------- gather x rows, cast bf16, fragment-major swizzle -------
__global__ void gather_cast_kernel(const float* __restrict__ x,
                                   const int* __restrict__ cnt,
                                   const int* __restrict__ basep,
                                   const int* __restrict__ etok,
                                   unsigned short* __restrict__ xgf)
{
    int e = blockIdx.x >> 6, g = blockIdx.x & 63;
    int n = cnt[e];
    if (g * 16 >= n) return;
    int tid = threadIdx.x;
    int row = g * 16 + (tid & 15);
    row = min(row, n - 1);
    int tok = etok[e * T_ + row];
    const float* xr = x + (size_t)tok * D_;
    unsigned short* dst = xgf + ((size_t)(basep[e] >> 4) + g) * 16384;
#pragma unroll
    for (int it = 0; it < 8; ++it) {
        int c = it * 16 + (tid >> 4);
        float4 v0 = *(const float4*)(xr + c * 8);
        float4 v1 = *(const float4*)(xr + c * 8 + 4);
        uint4 h;
        h.x = pack2bf(v0.x, v0.y); h.y = pack2bf(v0.z, v0.w);
        h.z = pack2bf(v1.x, v1.y); h.w = pack2bf(v1.z, v1.w);
        *(uint4*)(dst + c * 128 + (tid & 15) * 8) = h;
    }
}

// ------------------------------------------------- gemm1: xg@w1 + silu -----
// Barrier-free, LDS-free. Wave tile M=160 x (16g+16u). All load streams
// software-pipelined in registers: scales lead 4 steps, A and B lead 2 steps
// (consume-then-reissue ping-pong).
__global__ __launch_bounds__(256, 2) void gemm1_kernel(
    const unsigned short* __restrict__ xgf, const int* __restrict__ w1q,
    const float* __restrict__ w1s, const int* __restrict__ cnt,
    const int* __restrict__ basep, unsigned short* __restrict__ actf)
{
    int cg = blockIdx.x % 176, e = blockIdx.x / 176;
    int n = cnt[e];
    if (n <= 0) return;
    int npad = (n + 15) & ~15;
    int pb = basep[e];
    int tid = threadIdx.x, lane = tid & 63, w = tid >> 6;
    int l15 = lane & 15, lq = lane >> 4;
    int colg = w & 1, mh = w >> 1;
    int jcol = cg * 32 + colg * 16 + l15;

    const char* bg0 = (const char*)(w1q + ((size_t)e * 1024 + lq * 8) * TWO_I_ + jcol);
    const char* bu0 = bg0 + (size_t)I_ * 4;
    const float* sb = w1s + (size_t)e * 8 * TWO_I_ + jcol;

    for (int tb = 0; tb < npad; tb += 320) {
        const char* ap[10];
#pragma unroll
        for (int mi = 0; mi < 10; ++mi) {
            int R = tb + mh * 160 + mi * 16;
            R = min(R, npad - 16);
            ap[mi] = (const char*)xgf + (size_t)((pb + R) >> 4) * 32768
                   + lq * 256 + l15 * 16;
        }
        const char* bg = bg0;
        const char* bu = bu0;

        f32x4 accg[10], accu[10];
#pragma unroll
        for (int mi = 0; mi < 10; ++mi) {
            accg[mi] = (f32x4){0.f, 0.f, 0.f, 0.f};
            accu[mi] = (f32x4){0.f, 0.f, 0.f, 0.f};
        }
        int qg[2][8], qu[2][8];
        bf16x8 a[2][10];

        float sgc = sb[0], suc = sb[I_];
        // prologue: issue tau=0 and tau=1
#pragma unroll
        for (int pp = 0; pp < 2; ++pp) {
#pragma unroll
            for (int j = 0; j < 8; ++j) {
                qg[pp][j] = *(const int*)(bg + (size_t)j * 45056);
                qu[pp][j] = *(const int*)(bu + (size_t)j * 45056);
            }
            bg += 1441792; bu += 1441792;
#pragma unroll
            for (int mi = 0; mi < 10; ++mi) {
                a[pp][mi] = *(const bf16x8*)(ap[mi]);
                ap[mi] += 1024;
            }
        }

        for (int kg = 0; kg < 8; ++kg) {
            float sgn = 0.f, sun = 0.f;
            if (kg < 7) { sgn = sb[(size_t)(kg + 1) * TWO_I_];
                          sun = sb[(size_t)(kg + 1) * TWO_I_ + I_]; }
            float og = -8.f * sgc, ou = -8.f * suc;
#pragma unroll
            for (int ks = 0; ks < 4; ++ks) {
                const int p = ks & 1;
                union { unsigned u[4]; bf16x8 v; } fg, fu;
#pragma unroll
                for (int h = 0; h < 4; ++h) {
                    fg.u[h] = pack2bf((float)qg[p][2*h] * sgc + og,
                                      (float)qg[p][2*h+1] * sgc + og);
                    fu.u[h] = pack2bf((float)qu[p][2*h] * suc + ou,
                                      (float)qu[p][2*h+1] * suc + ou);
                }
                if (ks < 2 || kg < 7) {
#pragma unroll
                    for (int j = 0; j < 8; ++j) {
                        qg[p][j] = *(const int*)(bg + (size_t)j * 45056);
                        qu[p][j] = *(const int*)(bu + (size_t)j * 45056);
                    }
                    bg += 1441792; bu += 1441792;
                }
#pragma unroll
                for (int mi = 0; mi < 10; ++mi) {
                    accg[mi] = __builtin_amdgcn_mfma_f32_16x16x32_bf16(a[p][mi], fg.v, accg[mi], 0, 0, 0);
                    accu[mi] = __builtin_amdgcn_mfma_f32_16x16x32_bf16(a[p][mi], fu.v, accu[mi], 0, 0, 0);
                }
                if (ks < 2 || kg < 7) {
#pragma unroll
                    for (int mi = 0; mi < 10; ++mi) {
                        a[p][mi] = *(const bf16x8*)(ap[mi]);
                        ap[mi] += 1024;
                    }
                }
            }
            sgc = sgn; suc = sun;
        }
        // epilogue: silu(gate)*up -> act_f fragment-major
#pragma unroll
        for (int mi = 0; mi < 10; ++mi) {
#pragma unroll
            for (int r = 0; r < 4; ++r) {
                int m = tb + mh * 160 + mi * 16 + lq * 4 + r;
                if (m < npad) {
                    float gv = accg[mi][r], uv = accu[mi][r];
                    float av = gv / (1.f + __expf(-gv)) * uv;
                    int prow = pb + m;
                    size_t o = (size_t)(prow >> 4) * 90112 + (jcol >> 3) * 128
                             + (prow & 15) * 8 + (jcol & 7);
                    actf[o] = (unsigned short)f2bf(av);
                }
            }
        }
    }
}

// ---------------------------------------------------- gemm2: act@w2 --------
// Same pipelined structure. grid = E_*16dt*4seg. Wave M=160 x N=32,
// K/seg = 1408 (44 steps, 11 scale groups).
__global__ __launch_bounds__(256, 2) void gemm2_kernel(
    const unsigned short* __restrict__ actf, const int* __restrict__ w2q,
    const float* __restrict__ w2s, const int* __restrict__ cnt,
    const int* __restrict__ basep, float* __restrict__ y)
{
    int bid = blockIdx.x;
    int seg = bid & 3, dt = (bid >> 2) & 15, e = bid >> 6;
    int n = cnt[e];
    if (n <= 0) return;
    int npad = (n + 15) & ~15;
    int pb = basep[e];
    int tid = threadIdx.x, lane = tid & 63, w = tid >> 6;
    int l15 = lane & 15, lq = lane >> 4;
    int colg = w & 1, mh = w >> 1;
    int dcol = dt * 64 + colg * 32 + l15;

    const char* b00 = (const char*)(w2q + ((size_t)e * 5632 + seg * 1408 + lq * 8) * 1024 + dcol);
    const float* sb = w2s + ((size_t)e * 44 + seg * 11) * 1024 + dcol;
    float* yseg = y + (size_t)seg * NPAD_MAX * 1024;

    for (int tb = 0; tb < npad; tb += 320) {
        const char* ap[10];
#pragma unroll
        for (int mi = 0; mi < 10; ++mi) {
            int R = tb + mh * 160 + mi * 16;
            R = min(R, npad - 16);
            ap[mi] = (const char*)actf + (size_t)((pb + R) >> 4) * 180224
                   + seg * 45056 + lq * 256 + l15 * 16;
        }
        const char* b0 = b00;

        f32x4 acc0[10], acc1[10];
#pragma unroll
        for (int mi = 0; mi < 10; ++mi) {
            acc0[mi] = (f32x4){0.f, 0.f, 0.f, 0.f};
            acc1[mi] = (f32x4){0.f, 0.f, 0.f, 0.f};
        }
        int q0[2][8], q1[2][8];
        bf16x8 a[2][10];

        float s0c = sb[0], s1c = sb[16];
#pragma unroll
        for (int pp = 0; pp < 2; ++pp) {
#pragma unroll
            for (int j = 0; j < 8; ++j) {
                q0[pp][j] = *(const int*)(b0 + (size_t)j * 4096);
                q1[pp][j] = *(const int*)(b0 + 64 + (size_t)j * 4096);
            }
            b0 += 131072;
#pragma unroll
            for (int mi = 0; mi < 10; ++mi) {
                a[pp][mi] = *(const bf16x8*)(ap[mi]);
                ap[mi] += 1024;
            }
        }

        for (int kg = 0; kg < 11; ++kg) {
            float s0n = 0.f, s1n = 0.f;
            if (kg < 10) { s0n = sb[(size_t)(kg + 1) * 1024];
                           s1n = sb[(size_t)(kg + 1) * 1024 + 16]; }
            float o0 = -8.f * s0c, o1 = -8.f * s1c;
#pragma unroll
            for (int ks = 0; ks < 4; ++ks) {
                const int p = ks & 1;
                union { unsigned u[4]; bf16x8 v; } f0, f1;
#pragma unroll
                for (int h = 0; h < 4; ++h) {
                    f0.u[h] = pack2bf((float)q0[p][2*h] * s0c + o0,
                                      (float)q0[p][2*h+1] * s0c + o0);
                    f1.u[h] = pack2bf((float)q1[p][2*h] * s1c + o1,
                                      (float)q1[p][2*h+1] * s1c + o1);
                }
                if (ks < 2 || kg < 10) {
#pragma unroll
                    for (int j = 0; j < 8; ++j) {
                        q0[p][j] = *(const int*)(b0 + (size_t)j * 4096);
                        q1[p][j] = *(const int*)(b0 + 64 + (size_t)j * 4096);
                    }
                    b0 += 131072;
                }
#pragma unroll
                for (int mi = 0; mi < 10; ++mi) {
                    acc0[mi] = __builtin_amdgcn_mfma_f32_16x16x32_bf16(a[p][mi], f0.v, acc0[mi], 0, 0, 0);
                    acc1[mi] = __builtin_amdgcn_mfma_f32_16x16x32_bf16(a[p][mi], f1.v, acc1[mi], 0, 0, 0);
                }
                if (ks < 2 || kg < 10) {
#pragma unroll
                    for (int mi = 0; mi < 10; ++mi) {
                        a[p][mi] = *(const bf16x8*)(ap[mi]);
                        ap[mi] += 1024;
                    }
                }
            }
            s0c = s0n; s1c = s1n;
        }
#pragma unroll
        for (int mi = 0; mi < 10; ++mi) {
#pragma unroll
            for (int r = 0; r < 4; ++r) {
                int m = tb + mh * 160 + mi * 16 + lq * 4 + r;
                if (m < n) {
                    float* yr = yseg + (size_t)(pb + m) * 1024;
                    yr[dcol]      = acc0[mi][r];
                    yr[dcol + 16] = acc1[mi][r];
                }
            }
        }
    }
}

// --------------------------------------------------------------- combine ---
__global__ void combine_kernel(const float* __restrict__ y,
                               const int* __restrict__ eslot,
                               const float* __restrict__ tokw,
                               const int* __restrict__ basep,
                               float* __restrict__ out)
{
    int idx = blockIdx.x * blockDim.x + threadIdx.x;
    int t  = idx >> 8;
    int dc = idx & 255;
    int es0 = eslot[t * 2 + 0], es1 = eslot[t * 2 + 1];
    float w0 = tokw[t * 2 + 0], w1 = tokw[t * 2 + 1];
    int p0 = basep[es0 >> 10] + (es0 & 1023);
    int p1 = basep[es1 >> 10] + (es1 & 1023);
    const float4* y4 = (const float4*)y;
    float4 o = (float4){0.f, 0.f, 0.f, 0.f};
#pragma unroll
    for (int seg = 0; seg < 4; ++seg) {
        float4 a = y4[((size_t)seg * NPAD_MAX + p0) * 256 + dc];
        float4 b = y4[((size_t)seg * NPAD_MAX + p1) * 256 + dc];
        o.x += w0 * a.x + w1 * b.x;
        o.y += w0 * a.y + w1 * b.y;
        o.z += w0 * a.z + w1 * b.z;
        o.w += w0 * a.w + w1 * b.w;
    }
    ((float4*)out)[idx] = o;
}

// ---------------------------------------------------------------- launch ---
extern "C" void kernel_launch(void* const* d_in, const int* in_sizes, int n_in,
                              void* d_out, int out_size, void* d_ws, size_t ws_size,
                              hipStream_t stream)
{
    const float* x    = (const float*)d_in[0];
    const float* gate = (const float*)d_in[1];
    const int*   w1q  = (const int*)d_in[2];
    const int*   w2q  = (const int*)d_in[3];
    const float* w1s  = (const float*)d_in[4];
    const float* w2s  = (const float*)d_in[5];
    float* out = (float*)d_out;
    int*   wsi = (int*)d_ws;
    float* wsf = (float*)d_ws;

    int*   cnt   = wsi + WS_CNT;
    int*   basep = wsi + WS_BASEP;
    int*   eslot = wsi + WS_ESLOT;
    float* tokw  = wsf + WS_TOKW;
    int*   etok  = wsi + WS_ETOK;
    unsigned short* actf = (unsigned short*)((char*)d_ws + WS_ACTF_B);
    unsigned short* xgf  = (unsigned short*)((char*)d_ws + WS_XGF_B);
    float*          y    = (float*)((char*)d_ws + WS_Y_B);

    routing_kernel<<<1, 1024, 0, stream>>>(gate, cnt, basep, eslot, tokw, etok);
    gather_cast_kernel<<<E_ * 64, 256, 0, stream>>>(x, cnt, basep, etok, xgf);
    gemm1_kernel<<<E_ * 176, 256, 0, stream>>>(xgf, w1q, w1s, cnt, basep, actf);
    gemm2_kernel<<<E_ * 16 * 4, 256, 0, stream>>>(actf, w2q, w2s, cnt, basep, y);
    combine_kernel<<<(T_ * D_ / 4) / 256, 256, 0, stream>>>(y, eslot, tokw, basep, out);
}

// Round 6
// 1016.025 us; speedup vs baseline: 1.1157x; 1.1157x over previous
//
#include <hip/hip_runtime.h>
#include <cstdint>
#include <cstddef>

#define E_ 8
#define T_ 1024
#define D_ 1024
#define I_ 5632
#define TWO_I_ 11264
#define NPAD_MAX 2176                 /* 2048 + 8*16 */

// ws layout (bytes): int tables in [0,64K), then act_f, then xg_f, y overlays xg_f
#define WS_ACTF_B 65536
#define WS_XGF_B  (65536 + 24510464)              /* act_f = 136*180224      */
#define WS_Y_B    WS_XGF_B                        /* y overlays dead xg_f    */
// int-table offsets (units of 4 B)
#define WS_CNT   0
#define WS_BASEP 8
#define WS_ESLOT 16
#define WS_TOKW  2064
#define WS_ETOK  4112

typedef __attribute__((ext_vector_type(8))) __bf16 bf16x8;
typedef __attribute__((ext_vector_type(4))) float  f32x4;

__device__ __forceinline__ unsigned f2bf(float f) {
    unsigned u = __float_as_uint(f);
    u += 0x7fffu + ((u >> 16) & 1u);
    return u >> 16;
}
__device__ __forceinline__ unsigned pack2bf(float f0, float f1) {
    unsigned a0 = __float_as_uint(f0); a0 += 0x7fffu + ((a0 >> 16) & 1u);
    unsigned a1 = __float_as_uint(f1); a1 += 0x7fffu + ((a1 >> 16) & 1u);
    return (a0 >> 16) | (a1 & 0xffff0000u);
}

// ---------------------------------------------------------------- routing ---
__global__ void routing_kernel(const float* __restrict__ gate,
                               int* cnt, int* basep, int* eslot,
                               float* tokw, int* etok)
{
    int t = threadIdx.x;
    if (t < E_) cnt[t] = 0;
    __syncthreads();
    float g[E_];
#pragma unroll
    for (int e = 0; e < E_; ++e) g[e] = gate[t * E_ + e];
    int i0 = 0; float p0 = g[0];
#pragma unroll
    for (int e = 1; e < E_; ++e) if (g[e] > p0) { p0 = g[e]; i0 = e; }
    int i1 = -1; float p1 = -1e30f;
#pragma unroll
    for (int e = 0; e < E_; ++e) if (e != i0 && g[e] > p1) { p1 = g[e]; i1 = e; }
    float w0 = 1.0f / (1.0f + expf(p1 - p0));
    float w1 = 1.0f - w0;
    int s0 = atomicAdd(&cnt[i0], 1);
    int s1 = atomicAdd(&cnt[i1], 1);
    etok[i0 * T_ + s0] = t;
    etok[i1 * T_ + s1] = t;
    eslot[t * 2 + 0] = i0 * T_ + s0;  tokw[t * 2 + 0] = w0;
    eslot[t * 2 + 1] = i1 * T_ + s1;  tokw[t * 2 + 1] = w1;
    __syncthreads();
    if (t == 0) {
        int r = 0;
#pragma unroll
        for (int e = 0; e < E_; ++e) { basep[e] = r; r += (cnt[e] + 15) & ~15; }
    }
}

// ------------------- gather x rows, cast bf16, fragment-major swizzle -------
__global__ void gather_cast_kernel(const float* __restrict__ x,
                                   const int* __restrict__ cnt,
                                   const int* __restrict__ basep,
                                   const int* __restrict__ etok,
                                   unsigned short* __restrict__ xgf)
{
    int e = blockIdx.x >> 6, g = blockIdx.x & 63;
    int n = cnt[e];
    if (g * 16 >= n) return;
    int tid = threadIdx.x;
    int row = g * 16 + (tid & 15);
    row = min(row, n - 1);
    int tok = etok[e * T_ + row];
    const float* xr = x + (size_t)tok * D_;
    unsigned short* dst = xgf + ((size_t)(basep[e] >> 4) + g) * 16384;
#pragma unroll
    for (int it = 0; it < 8; ++it) {
        int c = it * 16 + (tid >> 4);
        float4 v0 = *(const float4*)(xr + c * 8);
        float4 v1 = *(const float4*)(xr + c * 8 + 4);
        uint4 h;
        h.x = pack2bf(v0.x, v0.y); h.y = pack2bf(v0.z, v0.w);
        h.z = pack2bf(v1.x, v1.y); h.w = pack2bf(v1.z, v1.w);
        *(uint4*)(dst + c * 128 + (tid & 15) * 8) = h;
    }
}

// ------------------------------------------------- gemm1: xg@w1 + silu -----
// Barrier-free, LDS-free. Wave tile M=128 x (16g+16u). B depth-2 reissue
// ping-pong (no extra regs), scales prefetched 1 group ahead, A single-buffer
// (LLC-hit). Register budget ~158 unified -> 3 waves/SIMD.
__global__ __launch_bounds__(256, 3) void gemm1_kernel(
    const unsigned short* __restrict__ xgf, const int* __restrict__ w1q,
    const float* __restrict__ w1s, const int* __restrict__ cnt,
    const int* __restrict__ basep, unsigned short* __restrict__ actf)
{
    int cg = blockIdx.x % 176, e = blockIdx.x / 176;
    int n = cnt[e];
    if (n <= 0) return;
    int npad = (n + 15) & ~15;
    int pb = basep[e];
    int tid = threadIdx.x, lane = tid & 63, w = tid >> 6;
    int l15 = lane & 15, lq = lane >> 4;
    int colg = w & 1, mh = w >> 1;
    int jcol = cg * 32 + colg * 16 + l15;

    const char* bg0 = (const char*)(w1q + ((size_t)e * 1024 + lq * 8) * TWO_I_ + jcol);
    const char* bu0 = bg0 + (size_t)I_ * 4;
    const float* sb = w1s + (size_t)e * 8 * TWO_I_ + jcol;

    for (int tb = 0; tb < npad; tb += 256) {
        int aoff[8];
#pragma unroll
        for (int mi = 0; mi < 8; ++mi) {
            int R = tb + mh * 128 + mi * 16;
            R = min(R, npad - 16);
            aoff[mi] = ((pb + R) >> 4) * 32768;
        }
        const char* abase = (const char*)xgf + lq * 256 + l15 * 16;
        const char* bg = bg0;
        const char* bu = bu0;

        f32x4 accg[8], accu[8];
#pragma unroll
        for (int mi = 0; mi < 8; ++mi) {
            accg[mi] = (f32x4){0.f, 0.f, 0.f, 0.f};
            accu[mi] = (f32x4){0.f, 0.f, 0.f, 0.f};
        }
        int qg[2][8], qu[2][8];
        // prologue: issue B for steps 0 and 1
#pragma unroll
        for (int pp = 0; pp < 2; ++pp) {
#pragma unroll
            for (int j = 0; j < 8; ++j) {
                qg[pp][j] = *(const int*)(bg + (size_t)j * 45056);
                qu[pp][j] = *(const int*)(bu + (size_t)j * 45056);
            }
            bg += 1441792; bu += 1441792;
        }
        float sgc = sb[0], suc = sb[I_];

        for (int kg = 0; kg < 8; ++kg) {
            float sgn = sgc, sun = suc;
            if (kg < 7) { sgn = sb[(size_t)(kg + 1) * TWO_I_];
                          sun = sb[(size_t)(kg + 1) * TWO_I_ + I_]; }
            float og = -8.f * sgc, ou = -8.f * suc;
            const char* akg = abase + kg * 4096;
#pragma unroll
            for (int ks = 0; ks < 4; ++ks) {
                const int p = ks & 1;
                // A loads for this step (issue first, consumed by MFMA below)
                bf16x8 a[8];
#pragma unroll
                for (int mi = 0; mi < 8; ++mi)
                    a[mi] = *(const bf16x8*)(akg + ks * 1024 + aoff[mi]);
                // dequant current B (issued 2 steps ago)
                union { unsigned u[4]; bf16x8 v; } fg, fu;
#pragma unroll
                for (int h = 0; h < 4; ++h) {
                    fg.u[h] = pack2bf((float)qg[p][2*h] * sgc + og,
                                      (float)qg[p][2*h+1] * sgc + og);
                    fu.u[h] = pack2bf((float)qu[p][2*h] * suc + ou,
                                      (float)qu[p][2*h+1] * suc + ou);
                }
                // reissue B into same buffer for step t+2
                if (ks < 2 || kg < 7) {
#pragma unroll
                    for (int j = 0; j < 8; ++j) {
                        qg[p][j] = *(const int*)(bg + (size_t)j * 45056);
                        qu[p][j] = *(const int*)(bu + (size_t)j * 45056);
                    }
                    bg += 1441792; bu += 1441792;
                }
#pragma unroll
                for (int mi = 0; mi < 8; ++mi) {
                    accg[mi] = __builtin_amdgcn_mfma_f32_16x16x32_bf16(a[mi], fg.v, accg[mi], 0, 0, 0);
                    accu[mi] = __builtin_amdgcn_mfma_f32_16x16x32_bf16(a[mi], fu.v, accu[mi], 0, 0, 0);
                }
            }
            sgc = sgn; suc = sun;
        }
        // epilogue: silu(gate)*up -> act_f fragment-major
#pragma unroll
        for (int mi = 0; mi < 8; ++mi) {
#pragma unroll
            for (int r = 0; r < 4; ++r) {
                int m = tb + mh * 128 + mi * 16 + lq * 4 + r;
                if (m < npad) {
                    float gv = accg[mi][r], uv = accu[mi][r];
                    float av = gv / (1.f + __expf(-gv)) * uv;
                    int prow = pb + m;
                    size_t o = (size_t)(prow >> 4) * 90112 + (jcol >> 3) * 128
                             + (prow & 15) * 8 + (jcol & 7);
                    actf[o] = (unsigned short)f2bf(av);
                }
            }
        }
    }
}

// ---------------------------------------------------- gemm2: act@w2 --------
// Same pipelined structure. grid = E_*16dt*4seg. Wave M=128 x N=32,
// K/seg = 1408 (44 steps, 11 scale groups).
__global__ __launch_bounds__(256, 3) void gemm2_kernel(
    const unsigned short* __restrict__ actf, const int* __restrict__ w2q,
    const float* __restrict__ w2s, const int* __restrict__ cnt,
    const int* __restrict__ basep, float* __restrict__ y)
{
    int bid = blockIdx.x;
    int seg = bid & 3, dt = (bid >> 2) & 15, e = bid >> 6;
    int n = cnt[e];
    if (n <= 0) return;
    int npad = (n + 15) & ~15;
    int pb = basep[e];
    int tid = threadIdx.x, lane = tid & 63, w = tid >> 6;
    int l15 = lane & 15, lq = lane >> 4;
    int colg = w & 1, mh = w >> 1;
    int dcol = dt * 64 + colg * 32 + l15;

    const char* b00 = (const char*)(w2q + ((size_t)e * 5632 + seg * 1408 + lq * 8) * 1024 + dcol);
    const float* sb = w2s + ((size_t)e * 44 + seg * 11) * 1024 + dcol;
    float* yseg = y + (size_t)seg * NPAD_MAX * 1024;

    for (int tb = 0; tb < npad; tb += 256) {
        int aoff[8];
#pragma unroll
        for (int mi = 0; mi < 8; ++mi) {
            int R = tb + mh * 128 + mi * 16;
            R = min(R, npad - 16);
            aoff[mi] = ((pb + R) >> 4) * 180224;
        }
        const char* abase = (const char*)actf + seg * 45056 + lq * 256 + l15 * 16;
        const char* b0 = b00;

        f32x4 acc0[8], acc1[8];
#pragma unroll
        for (int mi = 0; mi < 8; ++mi) {
            acc0[mi] = (f32x4){0.f, 0.f, 0.f, 0.f};
            acc1[mi] = (f32x4){0.f, 0.f, 0.f, 0.f};
        }
        int q0[2][8], q1[2][8];
#pragma unroll
        for (int pp = 0; pp < 2; ++pp) {
#pragma unroll
            for (int j = 0; j < 8; ++j) {
                q0[pp][j] = *(const int*)(b0 + (size_t)j * 4096);
                q1[pp][j] = *(const int*)(b0 + 64 + (size_t)j * 4096);
            }
            b0 += 131072;
        }
        float s0c = sb[0], s1c = sb[16];

        for (int kg = 0; kg < 11; ++kg) {
            float s0n = s0c, s1n = s1c;
            if (kg < 10) { s0n = sb[(size_t)(kg + 1) * 1024];
                           s1n = sb[(size_t)(kg + 1) * 1024 + 16]; }
            float o0 = -8.f * s0c, o1 = -8.f * s1c;
            const char* akg = abase + kg * 4096;
#pragma unroll
            for (int ks = 0; ks < 4; ++ks) {
                const int p = ks & 1;
                bf16x8 a[8];
#pragma unroll
                for (int mi = 0; mi < 8; ++mi)
                    a[mi] = *(const bf16x8*)(akg + ks * 1024 + aoff[mi]);
                union { unsigned u[4]; bf16x8 v; } f0, f1;
#pragma unroll
                for (int h = 0; h < 4; ++h) {
                    f0.u[h] = pack2bf((float)q0[p][2*h] * s0c + o0,
                                      (float)q0[p][2*h+1] * s0c + o0);
                    f1.u[h] = pack2bf((float)q1[p][2*h] * s1c + o1,
                                      (float)q1[p][2*h+1] * s1c + o1);
                }
                if (ks < 2 || kg < 10) {
#pragma unroll
                    for (int j = 0; j < 8; ++j) {
                        q0[p][j] = *(const int*)(b0 + (size_t)j * 4096);
                        q1[p][j] = *(const int*)(b0 + 64 + (size_t)j * 4096);
                    }
                    b0 += 131072;
                }
#pragma unroll
                for (int mi = 0; mi < 8; ++mi) {
                    acc0[mi] = __builtin_amdgcn_mfma_f32_16x16x32_bf16(a[mi], f0.v, acc0[mi], 0, 0, 0);
                    acc1[mi] = __builtin_amdgcn_mfma_f32_16x16x32_bf16(a[mi], f1.v, acc1[mi], 0, 0, 0);
                }
            }
            s0c = s0n; s1c = s1n;
        }
#pragma unroll
        for (int mi = 0; mi < 8; ++mi) {
#pragma unroll
            for (int r = 0; r < 4; ++r) {
                int m = tb + mh * 128 + mi * 16 + lq * 4 + r;
                if (m < n) {
                    float* yr = yseg + (size_t)(pb + m) * 1024;
                    yr[dcol]      = acc0[mi][r];
                    yr[dcol + 16] = acc1[mi][r];
                }
            }
        }
    }
}

// --------------------------------------------------------------- combine ---
__global__ void combine_kernel(const float* __restrict__ y,
                               const int* __restrict__ eslot,
                               const float* __restrict__ tokw,
                               const int* __restrict__ basep,
                               float* __restrict__ out)
{
    int idx = blockIdx.x * blockDim.x + threadIdx.x;
    int t  = idx >> 8;
    int dc = idx & 255;
    int es0 = eslot[t * 2 + 0], es1 = eslot[t * 2 + 1];
    float w0 = tokw[t * 2 + 0], w1 = tokw[t * 2 + 1];
    int p0 = basep[es0 >> 10] + (es0 & 1023);
    int p1 = basep[es1 >> 10] + (es1 & 1023);
    const float4* y4 = (const float4*)y;
    float4 o = (float4){0.f, 0.f, 0.f, 0.f};
#pragma unroll
    for (int seg = 0; seg < 4; ++seg) {
        float4 a = y4[((size_t)seg * NPAD_MAX + p0) * 256 + dc];
        float4 b = y4[((size_t)seg * NPAD_MAX + p1) * 256 + dc];
        o.x += w0 * a.x + w1 * b.x;
        o.y += w0 * a.y + w1 * b.y;
        o.z += w0 * a.z + w1 * b.z;
        o.w += w0 * a.w + w1 * b.w;
    }
    ((float4*)out)[idx] = o;
}

// ---------------------------------------------------------------- launch ---
extern "C" void kernel_launch(void* const* d_in, const int* in_sizes, int n_in,
                              void* d_out, int out_size, void* d_ws, size_t ws_size,
                              hipStream_t stream)
{
    const float* x    = (const float*)d_in[0];
    const float* gate = (const float*)d_in[1];
    const int*   w1q  = (const int*)d_in[2];
    const int*   w2q  = (const int*)d_in[3];
    const float* w1s  = (const float*)d_in[4];
    const float* w2s  = (const float*)d_in[5];
    float* out = (float*)d_out;
    int*   wsi = (int*)d_ws;
    float* wsf = (float*)d_ws;

    int*   cnt   = wsi + WS_CNT;
    int*   basep = wsi + WS_BASEP;
    int*   eslot = wsi + WS_ESLOT;
    float* tokw  = wsf + WS_TOKW;
    int*   etok  = wsi + WS_ETOK;
    unsigned short* actf = (unsigned short*)((char*)d_ws + WS_ACTF_B);
    unsigned short* xgf  = (unsigned short*)((char*)d_ws + WS_XGF_B);
    float*          y    = (float*)((char*)d_ws + WS_Y_B);

    routing_kernel<<<1, 1024, 0, stream>>>(gate, cnt, basep, eslot, tokw, etok);
    gather_cast_kernel<<<E_ * 64, 256, 0, stream>>>(x, cnt, basep, etok, xgf);
    gemm1_kernel<<<E_ * 176, 256, 0, stream>>>(xgf, w1q, w1s, cnt, basep, actf);
    gemm2_kernel<<<E_ * 16 * 4, 256, 0, stream>>>(actf, w2q, w2s, cnt, basep, y);
    combine_kernel<<<(T_ * D_ / 4) / 256, 256, 0, stream>>>(y, eslot, tokw, basep, out);
}

// Round 7
// 870.639 us; speedup vs baseline: 1.3020x; 1.1670x over previous
//
#include <hip/hip_runtime.h>
#include <cstdint>
#include <cstddef>

#define E_ 8
#define T_ 1024
#define D_ 1024
#define I_ 5632
#define TWO_I_ 11264
#define NPAD_MAX 2176                 /* 2048 + 8*16 */

// ws layout (bytes): int tables in [0,64K), then act_f, then xg_f, y overlays xg_f
#define WS_ACTF_B 65536
#define WS_XGF_B  (65536 + 24510464)              /* act_f = 136*180224      */
#define WS_Y_B    WS_XGF_B                        /* y overlays dead xg_f    */
// int-table offsets (units of 4 B)
#define WS_CNT   0
#define WS_BASEP 8
#define WS_ESLOT 16
#define WS_TOKW  2064
#define WS_ETOK  4112

typedef __attribute__((ext_vector_type(8))) __bf16 bf16x8;
typedef __attribute__((ext_vector_type(4))) float  f32x4;

__device__ __forceinline__ unsigned f2bf(float f) {
    unsigned u = __float_as_uint(f);
    u += 0x7fffu + ((u >> 16) & 1u);
    return u >> 16;
}
__device__ __forceinline__ unsigned pack2bf(float f0, float f1) {
    unsigned a0 = __float_as_uint(f0); a0 += 0x7fffu + ((a0 >> 16) & 1u);
    unsigned a1 = __float_as_uint(f1); a1 += 0x7fffu + ((a1 >> 16) & 1u);
    return (a0 >> 16) | (a1 & 0xffff0000u);
}

// ---------------------------------------------------------------- routing ---
__global__ void routing_kernel(const float* __restrict__ gate,
                               int* cnt, int* basep, int* eslot,
                               float* tokw, int* etok)
{
    int t = threadIdx.x;
    if (t < E_) cnt[t] = 0;
    __syncthreads();
    float g[E_];
#pragma unroll
    for (int e = 0; e < E_; ++e) g[e] = gate[t * E_ + e];
    int i0 = 0; float p0 = g[0];
#pragma unroll
    for (int e = 1; e < E_; ++e) if (g[e] > p0) { p0 = g[e]; i0 = e; }
    int i1 = -1; float p1 = -1e30f;
#pragma unroll
    for (int e = 0; e < E_; ++e) if (e != i0 && g[e] > p1) { p1 = g[e]; i1 = e; }
    float w0 = 1.0f / (1.0f + expf(p1 - p0));
    float w1 = 1.0f - w0;
    int s0 = atomicAdd(&cnt[i0], 1);
    int s1 = atomicAdd(&cnt[i1], 1);
    etok[i0 * T_ + s0] = t;
    etok[i1 * T_ + s1] = t;
    eslot[t * 2 + 0] = i0 * T_ + s0;  tokw[t * 2 + 0] = w0;
    eslot[t * 2 + 1] = i1 * T_ + s1;  tokw[t * 2 + 1] = w1;
    __syncthreads();
    if (t == 0) {
        int r = 0;
#pragma unroll
        for (int e = 0; e < E_; ++e) { basep[e] = r; r += (cnt[e] + 15) & ~15; }
    }
}

// ------------------- gather x rows, cast bf16, fragment-major swizzle -------
__global__ void gather_cast_kernel(const float* __restrict__ x,
                                   const int* __restrict__ cnt,
                                   const int* __restrict__ basep,
                                   const int* __restrict__ etok,
                                   unsigned short* __restrict__ xgf)
{
    int e = blockIdx.x >> 6, g = blockIdx.x & 63;
    int n = cnt[e];
    if (g * 16 >= n) return;
    int tid = threadIdx.x;
    int row = g * 16 + (tid & 15);
    row = min(row, n - 1);
    int tok = etok[e * T_ + row];
    const float* xr = x + (size_t)tok * D_;
    unsigned short* dst = xgf + ((size_t)(basep[e] >> 4) + g) * 16384;
#pragma unroll
    for (int it = 0; it < 8; ++it) {
        int c = it * 16 + (tid >> 4);
        float4 v0 = *(const float4*)(xr + c * 8);
        float4 v1 = *(const float4*)(xr + c * 8 + 4);
        uint4 h;
        h.x = pack2bf(v0.x, v0.y); h.y = pack2bf(v0.z, v0.w);
        h.z = pack2bf(v1.x, v1.y); h.w = pack2bf(v1.z, v1.w);
        *(uint4*)(dst + c * 128 + (tid & 15) * 8) = h;
    }
}

// ------------------------------------------------- gemm1: xg@w1 + silu -----
// 512 thr = 8 waves. Block: M=256, j-window 64 (gate + matching up), K=1024.
// B staged via contiguous k-row global reads -> packed q-bytes in LDS
// (pitch 136 B, <=2-way banks), double-buffered BK=64, 1 barrier/stage.
// Wave = mh(128 rows) x 16 cols (gate + up pair) -> acc 16 f32x4.
__global__ __launch_bounds__(512, 2) void gemm1_kernel(
    const unsigned short* __restrict__ xgf, const int* __restrict__ w1q,
    const float* __restrict__ w1s, const int* __restrict__ cnt,
    const int* __restrict__ basep, unsigned short* __restrict__ actf)
{
    int cg = blockIdx.x % 88, e = blockIdx.x / 88;
    int n = cnt[e];
    if (n <= 0) return;
    int npad = (n + 15) & ~15;
    int pb = basep[e];
    int tid = threadIdx.x, lane = tid & 63, w = tid >> 6;
    int l15 = lane & 15, lq = lane >> 4;
    int mh = w & 1, cp = w >> 1;            // cp 0..3
    int jloc = cp * 16 + l15;               // 0..63 within window

    __shared__ char bq[2][64 * 136];        // packed q bytes, [k][col] pitch 136

    // staging role: thread t -> row tid>>3 (0..63), 16 cols (tid&7)*16
    int srow = tid >> 3, sc8 = tid & 7;
    int scol = (sc8 < 4) ? (cg * 64 + sc8 * 16) : (I_ + cg * 64 + (sc8 - 4) * 16);
    const int* sgp = w1q + ((size_t)(e * 1024 + srow)) * TWO_I_ + scol;
    const size_t sstride = (size_t)64 * TWO_I_;     // ints per stage
    char* swr_base = (char*)0;  // set per-buffer below

    const char* abase = (const char*)xgf + lq * 256 + l15 * 16;
    const float* spg = w1s + (size_t)e * 8 * TWO_I_ + cg * 64 + jloc;
    const float* spu = spg + I_;

    for (int tb = 0; tb < npad; tb += 256) {
        int aoff[8];
#pragma unroll
        for (int mi = 0; mi < 8; ++mi) {
            int R = tb + mh * 128 + mi * 16;
            R = min(R, npad - 16);
            aoff[mi] = ((pb + R) >> 4) * 32768;
        }
        f32x4 accg[8], accu[8];
#pragma unroll
        for (int mi = 0; mi < 8; ++mi) {
            accg[mi] = (f32x4){0.f, 0.f, 0.f, 0.f};
            accu[mi] = (f32x4){0.f, 0.f, 0.f, 0.f};
        }
        // ---- prologue: stage 0
        {
            int4 v0 = *(const int4*)(sgp + 0);
            int4 v1 = *(const int4*)(sgp + 4);
            int4 v2 = *(const int4*)(sgp + 8);
            int4 v3 = *(const int4*)(sgp + 12);
            uint2 pA, pB;
            pA.x = (unsigned)v0.x | ((unsigned)v0.y << 8) | ((unsigned)v0.z << 16) | ((unsigned)v0.w << 24);
            pA.y = (unsigned)v1.x | ((unsigned)v1.y << 8) | ((unsigned)v1.z << 16) | ((unsigned)v1.w << 24);
            pB.x = (unsigned)v2.x | ((unsigned)v2.y << 8) | ((unsigned)v2.z << 16) | ((unsigned)v2.w << 24);
            pB.y = (unsigned)v3.x | ((unsigned)v3.y << 8) | ((unsigned)v3.z << 16) | ((unsigned)v3.w << 24);
            char* d = &bq[0][srow * 136 + sc8 * 16];
            *(uint2*)(d)     = pA;
            *(uint2*)(d + 8) = pB;
        }
        float sg = 0.f, su = 0.f;

        for (int s = 0; s < 16; ++s) {
            __syncthreads();
            // issue next stage's global loads
            int4 v0, v1, v2, v3;
            if (s < 15) {
                const int* p = sgp + (size_t)(s + 1) * sstride;
                v0 = *(const int4*)(p + 0);
                v1 = *(const int4*)(p + 4);
                v2 = *(const int4*)(p + 8);
                v3 = *(const int4*)(p + 12);
            }
            if ((s & 1) == 0) {
                int kg = s >> 1;
                sg = spg[(size_t)kg * TWO_I_];
                su = spu[(size_t)kg * TWO_I_];
            }
            float og = -8.f * sg, ou = -8.f * su;
            const unsigned char* cur = (const unsigned char*)bq[s & 1];
#pragma unroll
            for (int ks = 0; ks < 2; ++ks) {
                int t = s * 2 + ks;
                // B fragments from LDS bytes
                union { unsigned u[4]; bf16x8 v; } fg, fu;
#pragma unroll
                for (int h = 0; h < 4; ++h) {
                    int k0 = ks * 32 + lq * 8 + 2 * h;
                    float g0 = (float)cur[(k0 + 0) * 136 + jloc] * sg + og;
                    float g1 = (float)cur[(k0 + 1) * 136 + jloc] * sg + og;
                    float u0 = (float)cur[(k0 + 0) * 136 + 64 + jloc] * su + ou;
                    float u1 = (float)cur[(k0 + 1) * 136 + 64 + jloc] * su + ou;
                    fg.u[h] = pack2bf(g0, g1);
                    fu.u[h] = pack2bf(u0, u1);
                }
#pragma unroll
                for (int mi = 0; mi < 8; ++mi) {
                    bf16x8 a = *(const bf16x8*)(abase + t * 1024 + aoff[mi]);
                    accg[mi] = __builtin_amdgcn_mfma_f32_16x16x32_bf16(a, fg.v, accg[mi], 0, 0, 0);
                    accu[mi] = __builtin_amdgcn_mfma_f32_16x16x32_bf16(a, fu.v, accu[mi], 0, 0, 0);
                }
            }
            if (s < 15) {
                uint2 pA, pB;
                pA.x = (unsigned)v0.x | ((unsigned)v0.y << 8) | ((unsigned)v0.z << 16) | ((unsigned)v0.w << 24);
                pA.y = (unsigned)v1.x | ((unsigned)v1.y << 8) | ((unsigned)v1.z << 16) | ((unsigned)v1.w << 24);
                pB.x = (unsigned)v2.x | ((unsigned)v2.y << 8) | ((unsigned)v2.z << 16) | ((unsigned)v2.w << 24);
                pB.y = (unsigned)v3.x | ((unsigned)v3.y << 8) | ((unsigned)v3.z << 16) | ((unsigned)v3.w << 24);
                char* d = &bq[(s + 1) & 1][srow * 136 + sc8 * 16];
                *(uint2*)(d)     = pA;
                *(uint2*)(d + 8) = pB;
            }
        }
        // ---- epilogue: silu(gate)*up -> act_f fragment-major
        int jcol = cg * 64 + jloc;
#pragma unroll
        for (int mi = 0; mi < 8; ++mi) {
#pragma unroll
            for (int r = 0; r < 4; ++r) {
                int m = tb + mh * 128 + mi * 16 + lq * 4 + r;
                if (m < npad) {
                    float gv = accg[mi][r], uv = accu[mi][r];
                    float av = gv / (1.f + __expf(-gv)) * uv;
                    int prow = pb + m;
                    size_t o = (size_t)(prow >> 4) * 90112 + (jcol >> 3) * 128
                             + (prow & 15) * 8 + (jcol & 7);
                    actf[o] = (unsigned short)f2bf(av);
                }
            }
        }
        __syncthreads();   // protect bq before next tb pass
    }
}

// ---------------------------------------------------- gemm2: act@w2 --------
// Same structure. 256 blocks = e(8) x dt(8: 128-d-col windows) x seg(4).
// K/seg = 1408 -> 22 stages of BK=64. Wave = mh(128 rows) x (c0,c0+64) cols.
__global__ __launch_bounds__(512, 2) void gemm2_kernel(
    const unsigned short* __restrict__ actf, const int* __restrict__ w2q,
    const float* __restrict__ w2s, const int* __restrict__ cnt,
    const int* __restrict__ basep, float* __restrict__ y)
{
    int bid = blockIdx.x;
    int seg = bid & 3, dt = (bid >> 2) & 7, e = bid >> 5;
    int n = cnt[e];
    if (n <= 0) return;
    int npad = (n + 15) & ~15;
    int pb = basep[e];
    int tid = threadIdx.x, lane = tid & 63, w = tid >> 6;
    int l15 = lane & 15, lq = lane >> 4;
    int mh = w & 1, cp = w >> 1;
    int c0 = cp * 16 + l15;                 // LDS col; c1 = c0 + 64

    __shared__ char bq[2][64 * 136];

    int srow = tid >> 3, sc8 = tid & 7;
    const int* sgp = w2q + ((size_t)(e * 5632 + seg * 1408 + srow)) * 1024
                   + dt * 128 + sc8 * 16;
    const size_t sstride = (size_t)64 * 1024;

    const char* abase = (const char*)actf + seg * 45056 + lq * 256 + l15 * 16;
    const float* sp0 = w2s + ((size_t)e * 44 + seg * 11) * 1024 + dt * 128 + c0;
    float* yseg = y + (size_t)seg * NPAD_MAX * 1024;

    for (int tb = 0; tb < npad; tb += 256) {
        int aoff[8];
#pragma unroll
        for (int mi = 0; mi < 8; ++mi) {
            int R = tb + mh * 128 + mi * 16;
            R = min(R, npad - 16);
            aoff[mi] = ((pb + R) >> 4) * 180224;
        }
        f32x4 acc0[8], acc1[8];
#pragma unroll
        for (int mi = 0; mi < 8; ++mi) {
            acc0[mi] = (f32x4){0.f, 0.f, 0.f, 0.f};
            acc1[mi] = (f32x4){0.f, 0.f, 0.f, 0.f};
        }
        {
            int4 v0 = *(const int4*)(sgp + 0);
            int4 v1 = *(const int4*)(sgp + 4);
            int4 v2 = *(const int4*)(sgp + 8);
            int4 v3 = *(const int4*)(sgp + 12);
            uint2 pA, pB;
            pA.x = (unsigned)v0.x | ((unsigned)v0.y << 8) | ((unsigned)v0.z << 16) | ((unsigned)v0.w << 24);
            pA.y = (unsigned)v1.x | ((unsigned)v1.y << 8) | ((unsigned)v1.z << 16) | ((unsigned)v1.w << 24);
            pB.x = (unsigned)v2.x | ((unsigned)v2.y << 8) | ((unsigned)v2.z << 16) | ((unsigned)v2.w << 24);
            pB.y = (unsigned)v3.x | ((unsigned)v3.y << 8) | ((unsigned)v3.z << 16) | ((unsigned)v3.w << 24);
            char* d = &bq[0][srow * 136 + sc8 * 16];
            *(uint2*)(d)     = pA;
            *(uint2*)(d + 8) = pB;
        }
        float s0 = 0.f, s1 = 0.f;

        for (int s = 0; s < 22; ++s) {
            __syncthreads();
            int4 v0, v1, v2, v3;
            if (s < 21) {
                const int* p = sgp + (size_t)(s + 1) * sstride;
                v0 = *(const int4*)(p + 0);
                v1 = *(const int4*)(p + 4);
                v2 = *(const int4*)(p + 8);
                v3 = *(const int4*)(p + 12);
            }
            if ((s & 1) == 0) {
                int kg = s >> 1;
                s0 = sp0[(size_t)kg * 1024];
                s1 = sp0[(size_t)kg * 1024 + 64];
            }
            float o0 = -8.f * s0, o1 = -8.f * s1;
            const unsigned char* cur = (const unsigned char*)bq[s & 1];
#pragma unroll
            for (int ks = 0; ks < 2; ++ks) {
                int t = s * 2 + ks;
                union { unsigned u[4]; bf16x8 v; } f0, f1;
#pragma unroll
                for (int h = 0; h < 4; ++h) {
                    int k0 = ks * 32 + lq * 8 + 2 * h;
                    float a0 = (float)cur[(k0 + 0) * 136 + c0] * s0 + o0;
                    float a1 = (float)cur[(k0 + 1) * 136 + c0] * s0 + o0;
                    float b0 = (float)cur[(k0 + 0) * 136 + 64 + c0] * s1 + o1;
                    float b1 = (float)cur[(k0 + 1) * 136 + 64 + c0] * s1 + o1;
                    f0.u[h] = pack2bf(a0, a1);
                    f1.u[h] = pack2bf(b0, b1);
                }
#pragma unroll
                for (int mi = 0; mi < 8; ++mi) {
                    bf16x8 a = *(const bf16x8*)(abase + t * 1024 + aoff[mi]);
                    acc0[mi] = __builtin_amdgcn_mfma_f32_16x16x32_bf16(a, f0.v, acc0[mi], 0, 0, 0);
                    acc1[mi] = __builtin_amdgcn_mfma_f32_16x16x32_bf16(a, f1.v, acc1[mi], 0, 0, 0);
                }
            }
            if (s < 21) {
                uint2 pA, pB;
                pA.x = (unsigned)v0.x | ((unsigned)v0.y << 8) | ((unsigned)v0.z << 16) | ((unsigned)v0.w << 24);
                pA.y = (unsigned)v1.x | ((unsigned)v1.y << 8) | ((unsigned)v1.z << 16) | ((unsigned)v1.w << 24);
                pB.x = (unsigned)v2.x | ((unsigned)v2.y << 8) | ((unsigned)v2.z << 16) | ((unsigned)v2.w << 24);
                pB.y = (unsigned)v3.x | ((unsigned)v3.y << 8) | ((unsigned)v3.z << 16) | ((unsigned)v3.w << 24);
                char* d = &bq[(s + 1) & 1][srow * 136 + sc8 * 16];
                *(uint2*)(d)     = pA;
                *(uint2*)(d + 8) = pB;
            }
        }
        int dcol = dt * 128 + c0;
#pragma unroll
        for (int mi = 0; mi < 8; ++mi) {
#pragma unroll
            for (int r = 0; r < 4; ++r) {
                int m = tb + mh * 128 + mi * 16 + lq * 4 + r;
                if (m < n) {
                    float* yr = yseg + (size_t)(pb + m) * 1024;
                    yr[dcol]      = acc0[mi][r];
                    yr[dcol + 64] = acc1[mi][r];
                }
            }
        }
        __syncthreads();
    }
}

// --------------------------------------------------------------- combine ---
__global__ void combine_kernel(const float* __restrict__ y,
                               const int* __restrict__ eslot,
                               const float* __restrict__ tokw,
                               const int* __restrict__ basep,
                               float* __restrict__ out)
{
    int idx = blockIdx.x * blockDim.x + threadIdx.x;
    int t  = idx >> 8;
    int dc = idx & 255;
    int es0 = eslot[t * 2 + 0], es1 = eslot[t * 2 + 1];
    float w0 = tokw[t * 2 + 0], w1 = tokw[t * 2 + 1];
    int p0 = basep[es0 >> 10] + (es0 & 1023);
    int p1 = basep[es1 >> 10] + (es1 & 1023);
    const float4* y4 = (const float4*)y;
    float4 o = (float4){0.f, 0.f, 0.f, 0.f};
#pragma unroll
    for (int seg = 0; seg < 4; ++seg) {
        float4 a = y4[((size_t)seg * NPAD_MAX + p0) * 256 + dc];
        float4 b = y4[((size_t)seg * NPAD_MAX + p1) * 256 + dc];
        o.x += w0 * a.x + w1 * b.x;
        o.y += w0 * a.y + w1 * b.y;
        o.z += w0 * a.z + w1 * b.z;
        o.w += w0 * a.w + w1 * b.w;
    }
    ((float4*)out)[idx] = o;
}

// ---------------------------------------------------------------- launch ---
extern "C" void kernel_launch(void* const* d_in, const int* in_sizes, int n_in,
                              void* d_out, int out_size, void* d_ws, size_t ws_size,
                              hipStream_t stream)
{
    const float* x    = (const float*)d_in[0];
    const float* gate = (const float*)d_in[1];
    const int*   w1q  = (const int*)d_in[2];
    const int*   w2q  = (const int*)d_in[3];
    const float* w1s  = (const float*)d_in[4];
    const float* w2s  = (const float*)d_in[5];
    float* out = (float*)d_out;
    int*   wsi = (int*)d_ws;
    float* wsf = (float*)d_ws;

    int*   cnt   = wsi + WS_CNT;
    int*   basep = wsi + WS_BASEP;
    int*   eslot = wsi + WS_ESLOT;
    float* tokw  = wsf + WS_TOKW;
    int*   etok  = wsi + WS_ETOK;
    unsigned short* actf = (unsigned short*)((char*)d_ws + WS_ACTF_B);
    unsigned short* xgf  = (unsigned short*)((char*)d_ws + WS_XGF_B);
    float*          y    = (float*)((char*)d_ws + WS_Y_B);

    routing_kernel<<<1, 1024, 0, stream>>>(gate, cnt, basep, eslot, tokw, etok);
    gather_cast_kernel<<<E_ * 64, 256, 0, stream>>>(x, cnt, basep, etok, xgf);
    gemm1_kernel<<<E_ * 88, 512, 0, stream>>>(xgf, w1q, w1s, cnt, basep, actf);
    gemm2_kernel<<<256, 512, 0, stream>>>(actf, w2q, w2s, cnt, basep, y);
    combine_kernel<<<(T_ * D_ / 4) / 256, 256, 0, stream>>>(y, eslot, tokw, basep, out);
}